// Round 1
// baseline (249.969 us; speedup 1.0000x reference)
//
#include <hip/hip_runtime.h>

#define NTOT 100000
#define DIM 256

typedef float f32x4 __attribute__((ext_vector_type(4)));
typedef short s16x8 __attribute__((ext_vector_type(8)));

__device__ __forceinline__ unsigned short bfbits(float f) {
    return __builtin_bit_cast(unsigned short, (__bf16)f);
}
__device__ __forceinline__ unsigned int packbf2(float a, float b) {
    return (unsigned int)bfbits(a) | ((unsigned int)bfbits(b) << 16);
}
__device__ __forceinline__ s16x8 cvt8(const float* __restrict__ p) {
    f32x4 lo = *(const f32x4*)p;
    f32x4 hi = *(const f32x4*)(p + 4);
    s16x8 r;
#pragma unroll
    for (int e = 0; e < 4; ++e) r[e] = (short)bfbits(lo[e]);
#pragma unroll
    for (int e = 0; e < 4; ++e) r[4 + e] = (short)bfbits(hi[e]);
    return r;
}

// ---------------- kernel 1: Cayley weights -------------------------------
// base_k = (t-i)/(t+i), t = h*(lam_k - alpha).  br[j][k]=Re(base^(j+1)),
// bi[j][k]=Im(base^(j+1)), j=0..7.
__global__ void k_weights(const float* __restrict__ ev, const float* __restrict__ hp,
                          const float* __restrict__ ap, float* __restrict__ br,
                          float* __restrict__ bi) {
    int k = threadIdx.x;
    float h = hp[0], alpha = ap[0];
    float t = h * (ev[k] - alpha);
    float inv = 1.0f / (t * t + 1.0f);
    float b_re = (t * t - 1.0f) * inv;   // Re (t-i)/(t+i)
    float b_im = -2.0f * t * inv;        // Im
    float cr = b_re, ci = b_im;
    br[k] = cr; bi[k] = ci;
#pragma unroll
    for (int j = 1; j < 8; ++j) {
        float nr = cr * b_re - ci * b_im;
        float ni = cr * b_im + ci * b_re;
        cr = nr; ci = ni;
        br[j * 256 + k] = cr;
        bi[j * 256 + k] = ci;
    }
}

// ---------------- kernel 2: P_partial = E^T @ x over an N-chunk ----------
// grid = 2*chunks; block 512 (8 waves).  Block tile: 128 (k) x 256 (i).
// LDS staging transposed (reduction-dim contiguous), XOR-swizzled.
__global__ __launch_bounds__(512, 4) void k_gemm1(
    const float* __restrict__ E, const float* __restrict__ X,
    float* __restrict__ Ppart, int NB) {
    int bx = blockIdx.x;
    int tile = bx & 1;
    int chunk = bx >> 1;
    int k0 = tile * 128;
    int nStart = chunk * NB;
    int nEnd = min(nStart + NB, NTOT);

    __shared__ alignas(16) unsigned char sm[(128 + 256) * 64];
    unsigned char* Et = sm;              // [128][32] bf16 swizzled (8 KB)
    unsigned char* Xt = sm + 128 * 64;   // [256][32] bf16 swizzled (16 KB)

    int t = threadIdx.x;
    int lane = t & 63;
    int w = t >> 6;
    int wk = w & 1;        // k-half (64)
    int wi = w >> 1;       // i-quarter (64)
    int l15 = lane & 15, lhi = lane >> 4;

    int ek = t & 127, enb = t >> 7;      // E staging: k 0..127, n-group 0..3
    int xi = t & 255, xng = t >> 8;      // X staging: i 0..255, n-group 0..1

    f32x4 acc[4][4] = {};

    for (int n0 = nStart; n0 < nEnd; n0 += 32) {
        // stage E tile [n0..n0+31][k0..k0+127] -> Et[k][n]
        {
            float v[8];
#pragma unroll
            for (int s = 0; s < 8; ++s) {
                int n = n0 + enb * 8 + s;
                int nc = (n < nEnd) ? n : nStart;           // clamp to valid addr
                float vv = E[nc * DIM + k0 + ek];
                v[s] = (n < nEnd) ? vv : 0.0f;
            }
#pragma unroll
            for (int p = 0; p < 4; ++p) {
                int byte = (ek * 64 + (enb * 8 + 2 * p) * 2) ^ ((ek & 7) << 4);
                *(unsigned int*)(Et + byte) = packbf2(v[2 * p], v[2 * p + 1]);
            }
        }
        // stage X tile [n0..n0+31][0..255] -> Xt[i][n], two passes of 8 rows
#pragma unroll
        for (int hh = 0; hh < 2; ++hh) {
            float v[8];
#pragma unroll
            for (int s = 0; s < 8; ++s) {
                int n = n0 + xng * 16 + hh * 8 + s;
                int nc = (n < nEnd) ? n : nStart;
                float vv = X[nc * DIM + xi];
                v[s] = (n < nEnd) ? vv : 0.0f;
            }
#pragma unroll
            for (int p = 0; p < 4; ++p) {
                int byte = (xi * 64 + (xng * 16 + hh * 8 + 2 * p) * 2) ^ ((xi & 7) << 4);
                *(unsigned int*)(Xt + byte) = packbf2(v[2 * p], v[2 * p + 1]);
            }
        }
        __syncthreads();

        s16x8 a[4], b[4];
#pragma unroll
        for (int m = 0; m < 4; ++m) {
            int kk = wk * 64 + m * 16 + l15;
            int byte = (kk * 64 + lhi * 16) ^ ((kk & 7) << 4);
            a[m] = *(const s16x8*)(Et + byte);
        }
#pragma unroll
        for (int c = 0; c < 4; ++c) {
            int ii = wi * 64 + c * 16 + l15;
            int byte = (ii * 64 + lhi * 16) ^ ((ii & 7) << 4);
            b[c] = *(const s16x8*)(Xt + byte);
        }
#pragma unroll
        for (int m = 0; m < 4; ++m)
#pragma unroll
            for (int c = 0; c < 4; ++c)
                acc[m][c] = __builtin_amdgcn_mfma_f32_16x16x32_bf16(a[m], b[c], acc[m][c], 0, 0, 0);
        __syncthreads();
    }

    float* dst = Ppart + chunk * (256 * 256);
#pragma unroll
    for (int m = 0; m < 4; ++m) {
        int kk = k0 + wk * 64 + m * 16 + lhi * 4;
#pragma unroll
        for (int c = 0; c < 4; ++c) {
            int ii = wi * 64 + c * 16 + l15;
#pragma unroll
            for (int r = 0; r < 4; ++r)
                dst[(kk + r) * 256 + ii] = acc[m][c][r];
        }
    }
}

// ---------------- kernel 3: reduce partials, emit Pb (bf16) --------------
__global__ void k_reduceP(const float* __restrict__ Ppart,
                          unsigned short* __restrict__ Pb, int chunks) {
    int g = blockIdx.x * 256 + threadIdx.x;   // 0..65535
    float s = 0.f;
    for (int c = 0; c < chunks; ++c) s += Ppart[c * 65536 + g];
    Pb[g] = bfbits(s);
}

// ---------------- kernel 4: T[c] = P @ W_c^T (17 small GEMMs) ------------
// grid = 17*4 (c, k-tile of 64); block 256 (4 waves = 4 o-quarters).
__global__ __launch_bounds__(256, 4) void k_smallgemm(
    const unsigned short* __restrict__ Pb, const float* __restrict__ c0,
    const float* __restrict__ cjr, const float* __restrict__ cji,
    float* __restrict__ T) {
    int c = blockIdx.x >> 2;
    int k0 = (blockIdx.x & 3) * 64;
    const float* W = (c == 0) ? c0 : (c <= 8 ? (cjr + (c - 1) * 65536)
                                             : (cji + (c - 9) * 65536));
    int t = threadIdx.x, lane = t & 63, wi = t >> 6;
    int l15 = lane & 15, lhi = lane >> 4;
    f32x4 acc[4][4] = {};
    for (int ks = 0; ks < 256; ks += 32) {
        s16x8 a[4], b[4];
#pragma unroll
        for (int m = 0; m < 4; ++m)
            a[m] = *(const s16x8*)(Pb + (k0 + m * 16 + l15) * 256 + ks + lhi * 8);
#pragma unroll
        for (int cf = 0; cf < 4; ++cf)
            b[cf] = cvt8(W + (wi * 64 + cf * 16 + l15) * 256 + ks + lhi * 8);
#pragma unroll
        for (int m = 0; m < 4; ++m)
#pragma unroll
            for (int cf = 0; cf < 4; ++cf)
                acc[m][cf] = __builtin_amdgcn_mfma_f32_16x16x32_bf16(a[m], b[cf], acc[m][cf], 0, 0, 0);
    }
    float* dst = T + c * 65536;
#pragma unroll
    for (int m = 0; m < 4; ++m) {
        int kk = k0 + m * 16 + lhi * 4;
#pragma unroll
        for (int cf = 0; cf < 4; ++cf) {
            int oo = wi * 64 + cf * 16 + l15;
#pragma unroll
            for (int r = 0; r < 4; ++r)
                dst[(kk + r) * 256 + oo] = acc[m][cf][r];
        }
    }
}

// ---------------- kernel 5: combine T -> Qt bf16 (transposed) ------------
// Q[k,o] = T0 + 2*sum_j (br[j,k]*Tr[j] - bi[j,k]*Ti[j]); Qt[o][k] = bf16(Q)
__global__ void k_combine(const float* __restrict__ T, const float* __restrict__ br,
                          const float* __restrict__ bi, unsigned short* __restrict__ Qt) {
    int k = blockIdx.x;
    int o = threadIdx.x;
    float q = T[k * 256 + o];
#pragma unroll
    for (int j = 0; j < 8; ++j) {
        float brv = br[j * 256 + k], biv = bi[j * 256 + k];
        q += 2.f * (brv * T[(1 + j) * 65536 + k * 256 + o]
                  - biv * T[(9 + j) * 65536 + k * 256 + o]);
    }
    Qt[o * 256 + k] = bfbits(q);
}

// ---------------- kernel 6: out = E @ Q ----------------------------------
// grid = ceil(N/64); block 256 (4 waves = 4 o-quarters). LDS-free:
// A-frags straight from E rows (f32->bf16 in reg), B-frags from Qt rows.
__global__ __launch_bounds__(256, 4) void k_gemm2(
    const float* __restrict__ E, const unsigned short* __restrict__ Qt,
    float* __restrict__ out) {
    int n0 = blockIdx.x * 64;
    int t = threadIdx.x, lane = t & 63, wi = t >> 6;
    int l15 = lane & 15, lhi = lane >> 4;
    f32x4 acc[4][4] = {};
    for (int ks = 0; ks < 256; ks += 32) {
        s16x8 a[4], b[4];
#pragma unroll
        for (int m = 0; m < 4; ++m) {
            int n = n0 + m * 16 + l15;
            if (n > NTOT - 1) n = NTOT - 1;
            a[m] = cvt8(E + n * DIM + ks + lhi * 8);
        }
#pragma unroll
        for (int cf = 0; cf < 4; ++cf)
            b[cf] = *(const s16x8*)(Qt + (wi * 64 + cf * 16 + l15) * 256 + ks + lhi * 8);
#pragma unroll
        for (int m = 0; m < 4; ++m)
#pragma unroll
            for (int cf = 0; cf < 4; ++cf)
                acc[m][cf] = __builtin_amdgcn_mfma_f32_16x16x32_bf16(a[m], b[cf], acc[m][cf], 0, 0, 0);
    }
#pragma unroll
    for (int m = 0; m < 4; ++m) {
#pragma unroll
        for (int r = 0; r < 4; ++r) {
            int n = n0 + m * 16 + lhi * 4 + r;
            if (n < NTOT) {
#pragma unroll
                for (int cf = 0; cf < 4; ++cf)
                    out[n * 256 + wi * 64 + cf * 16 + l15] = acc[m][cf][r];
            }
        }
    }
}

// ---------------- host ---------------------------------------------------
extern "C" void kernel_launch(void* const* d_in, const int* in_sizes, int n_in,
                              void* d_out, int out_size, void* d_ws, size_t ws_size,
                              hipStream_t stream) {
    const float* x   = (const float*)d_in[0];
    const float* ev  = (const float*)d_in[1];
    const float* E   = (const float*)d_in[2];
    const float* hp  = (const float*)d_in[3];
    const float* ap  = (const float*)d_in[4];
    const float* c0  = (const float*)d_in[5];
    const float* cjr = (const float*)d_in[6];
    const float* cji = (const float*)d_in[7];
    float* out = (float*)d_out;

    char* ws = (char*)d_ws;
    float* br          = (float*)(ws + 0);          // 8 KB
    float* bi          = (float*)(ws + 8192);       // 8 KB
    unsigned short* Pb = (unsigned short*)(ws + 278528);   // 128 KB
    unsigned short* Qt = (unsigned short*)(ws + 409600);   // 128 KB
    float* T           = (float*)(ws + 540672);     // 17*256KB = 4.45 MB
    const size_t ppart_off = 4997120;
    float* Ppart       = (float*)(ws + ppart_off);

    size_t avail = (ws_size > ppart_off) ? (ws_size - ppart_off) : 0;
    int chunks = (int)(avail / 262144);
    if (chunks > 256) chunks = 256;
    if (chunks < 1) chunks = 1;
    int NB = (NTOT + chunks - 1) / chunks;

    k_weights<<<1, 256, 0, stream>>>(ev, hp, ap, br, bi);
    k_gemm1<<<2 * chunks, 512, 0, stream>>>(E, x, Ppart, NB);
    k_reduceP<<<256, 256, 0, stream>>>(Ppart, Pb, chunks);
    k_smallgemm<<<17 * 4, 256, 0, stream>>>(Pb, c0, cjr, cji, T);
    k_combine<<<256, 256, 0, stream>>>(T, br, bi, Qt);
    k_gemm2<<<(NTOT + 63) / 64, 256, 0, stream>>>(E, Qt, out);
}